// Round 2
// baseline (20549.197 us; speedup 1.0000x reference)
//
#include <hip/hip_runtime.h>
#include <math.h>

#define HF 32
#define WF 128
#define HW 4096
#define C_DIM 684
#define H_DIM 256
#define A_DIM 512
#define V_DIM 415
#define PADR 42
#define PADC 144
#define T_STEPS 64
#define NSEG 16
#define NBLK 256
#define NCTX 171   // 171 blocks x 4 channels = 684

// ---------------- workspace layout (float offsets) ----------------
constexpr int CT_OFF      = 0;                          // cnn_trans [hw][a]
constexpr int KM_OFF      = CT_OFF + HW * A_DIM;        // merged kernel [121][512]
constexpr int APAD_OFF    = KM_OFF + 121 * A_DIM;       // padded alpha_sum [42][144]
constexpr int MASK_OFF    = APAD_OFF + PADR * PADC;     // [4096]
constexpr int EXP_OFF     = MASK_OFF + HW;              // exp(energy) [4096]
constexpr int AVG_OFF     = EXP_OFF + HW;               // [684] pad 704
constexpr int HBUF0_OFF   = AVG_OFF + 704;
constexpr int HBUF1_OFF   = HBUF0_OFF + 256;
constexpr int MSUM_OFF    = HBUF1_OFF + 256;            // [1] pad 16
constexpr int WORDS_OFF   = MSUM_OFF + 16;              // 2 ints, pad 16
constexpr int BAR_OFF     = WORDS_OFF + 16;             // cnt,gen ints, pad 16
constexpr int PSUM_OFF    = BAR_OFF + 16;               // [256] per-block exp sums
constexpr int PQ_OFF      = PSUM_OFF + 256;             // [16][512]
constexpr int PGHO_OFF    = PQ_OFF + NSEG * 512;        // [16][768]
constexpr int PGHIN0_OFF  = PGHO_OFF + NSEG * 768;      // [16][768] ping
constexpr int PGHIN1_OFF  = PGHIN0_OFF + NSEG * 768;    // pong
constexpr int PGIO2_OFF   = PGHIN1_OFF + NSEG * 768;    // [171][768]
constexpr int PSC2_OFF    = PGIO2_OFF + NCTX * 768;     // [171][128]
constexpr int GI_OFF      = PSC2_OFF + NCTX * 128;      // [415][768]
constexpr int SE_OFF      = GI_OFF + V_DIM * 768;       // [415][128]
constexpr int WQT_OFF     = SE_OFF + V_DIM * 128;       // [256][512]
constexpr int WHHTIN_OFF  = WQT_OFF + 256 * 512;        // [256][768]
constexpr int WHHTOUT_OFF = WHHTIN_OFF + 256 * 768;     // [256][768]
constexpr int WIHTOUT_OFF = WHHTOUT_OFF + 256 * 768;    // [684][768]
constexpr int WCT_OFF     = WIHTOUT_OFF + 684 * 768;    // [684][128]
constexpr int WST_OFF     = WCT_OFF + 684 * 128;        // [256][128]
constexpr int WVT_OFF     = WST_OFF + 256 * 128;        // [128][415]
constexpr int WS_END      = WVT_OFF + 128 * V_DIM;      // ~4.02M floats = 16.1 MB

__device__ __forceinline__ float sigmoidf_(float x) { return 1.f / (1.f + expf(-x)); }
__device__ __forceinline__ float ftanh(float x) {
  float e = __expf(2.f * x);
  return 1.f - 2.f / (e + 1.f);
}

__device__ __forceinline__ float compute_h1_row(const float* ws, int j, int word, int t,
                                                const float* bhh_in) {
  const float* gi = ws + GI_OFF + word * 768;
  const float* pg = ws + ((t & 1) ? PGHIN1_OFF : PGHIN0_OFF);
  float gh0 = bhh_in[j], gh1 = bhh_in[256 + j], gh2 = bhh_in[512 + j];
#pragma unroll
  for (int s = 0; s < NSEG; s++) {
    gh0 += pg[s * 768 + j];
    gh1 += pg[s * 768 + 256 + j];
    gh2 += pg[s * 768 + 512 + j];
  }
  float r = sigmoidf_(gi[j] + gh0);
  float z = sigmoidf_(gi[256 + j] + gh1);
  float n = tanhf(gi[512 + j] + r * gh2);
  float hp = ws[((t & 1) ? HBUF1_OFF : HBUF0_OFF) + j];
  return (1.f - z) * n + z * hp;
}

// device-scope grid barrier (sense-free, monotone generation)
__device__ __forceinline__ void gbar(int* cnt, int* gen) {
  __syncthreads();
  if (threadIdx.x == 0) {
    int g = __hip_atomic_load(gen, __ATOMIC_RELAXED, __HIP_MEMORY_SCOPE_AGENT);
    int t = __hip_atomic_fetch_add(cnt, 1, __ATOMIC_ACQ_REL, __HIP_MEMORY_SCOPE_AGENT);
    if (t == NBLK - 1) {
      __hip_atomic_store(cnt, 0, __ATOMIC_RELAXED, __HIP_MEMORY_SCOPE_AGENT);
      __hip_atomic_fetch_add(gen, 1, __ATOMIC_ACQ_REL, __HIP_MEMORY_SCOPE_AGENT);
    } else {
      while (__hip_atomic_load(gen, __ATOMIC_RELAXED, __HIP_MEMORY_SCOPE_AGENT) <= g) {
        __builtin_amdgcn_s_sleep(1);
      }
      (void)__hip_atomic_load(gen, __ATOMIC_ACQUIRE, __HIP_MEMORY_SCOPE_AGENT);
    }
  }
  __syncthreads();
}

// ---------------- precompute kernels ----------------

__global__ void k_init(const float* __restrict__ imask, float* ws) {
  __shared__ float red[4];
  int tid = threadIdx.x;
  float s = 0.f;
  for (int i = tid; i < HW; i += 256) {
    int h = i >> 7, w = i & 127;
    float m = imask[h * 16 * 2048 + w * 16];
    ws[MASK_OFF + i] = m;
    s += m;
  }
  for (int i = tid; i < PADR * PADC; i += 256) ws[APAD_OFF + i] = 0.f;
#pragma unroll
  for (int off = 32; off; off >>= 1) s += __shfl_xor(s, off, 64);
  if ((tid & 63) == 0) red[tid >> 6] = s;
  __syncthreads();
  if (tid == 0) {
    ws[MSUM_OFF] = red[0] + red[1] + red[2] + red[3];
    ((int*)ws)[WORDS_OFF] = 1;  // emb0 = emb_table[1]
    ((int*)ws)[BAR_OFF] = 0;
    ((int*)ws)[BAR_OFF + 1] = 0;
  }
}

__global__ void k_avg(const float* __restrict__ cnn, float* ws) {
  __shared__ float red[4];
  int c = blockIdx.x, tid = threadIdx.x;
  const float* row = cnn + c * HW;
  float s = 0.f;
  for (int i = tid; i < HW; i += 256) s += ws[MASK_OFF + i] * row[i];
#pragma unroll
  for (int off = 32; off; off >>= 1) s += __shfl_xor(s, off, 64);
  if ((tid & 63) == 0) red[tid >> 6] = s;
  __syncthreads();
  if (tid == 0) ws[AVG_OFF + c] = (red[0] + red[1] + red[2] + red[3]) / ws[MSUM_OFF];
}

__global__ void k_h0(const float* __restrict__ W_init, const float* __restrict__ b_init, float* ws) {
  __shared__ float a_s[C_DIM];
  int tid = threadIdx.x;
  for (int i = tid; i < C_DIM; i += 256) a_s[i] = ws[AVG_OFF + i];
  __syncthreads();
  const float* wr = W_init + tid * C_DIM;
  float s = b_init[tid];
  for (int k = 0; k < C_DIM; k++) s += a_s[k] * wr[k];
  ws[HBUF0_OFF + tid] = tanhf(s);
}

__global__ __launch_bounds__(512) void k_km(const float* __restrict__ convk,
                                            const float* __restrict__ Wcov, float* ws) {
  __shared__ float kt[256];
  int t = blockIdx.x, a = threadIdx.x;
  if (a < 256) kt[a] = convk[a * 121 + t];
  __syncthreads();
  const float* wr = Wcov + a * 256;
  float s = 0.f;
  for (int c = 0; c < 256; c++) s += kt[c] * wr[c];
  ws[KM_OFF + t * A_DIM + a] = s;
}

__global__ void k_ct(const float* __restrict__ cnn, const float* __restrict__ Wproj,
                     const float* __restrict__ bproj, float* ws) {
  __shared__ float As[8][128];
  __shared__ float Bs[8][64];
  int hw0 = blockIdx.x * 128;
  int a0 = blockIdx.y * 64;
  int tid = threadIdx.x;
  int tx = tid & 15, ty = tid >> 4;
  float acc[8][4];
#pragma unroll
  for (int i = 0; i < 8; i++)
#pragma unroll
    for (int j = 0; j < 4; j++) acc[i][j] = 0.f;

  for (int c0 = 0; c0 < C_DIM; c0 += 8) {
    {
      int kk = tid >> 5;
      int m4 = (tid & 31) * 4;
      int c = c0 + kk;
      float4 v = make_float4(0.f, 0.f, 0.f, 0.f);
      if (c < C_DIM) v = *(const float4*)(cnn + c * HW + hw0 + m4);
      *(float4*)&As[kk][m4] = v;
    }
    {
      int n = tid & 63;
      int kk0 = (tid >> 6) * 2;
      const float* wr = Wproj + (a0 + n) * C_DIM + c0;
      Bs[kk0][n]     = (c0 + kk0 < C_DIM) ? wr[kk0] : 0.f;
      Bs[kk0 + 1][n] = (c0 + kk0 + 1 < C_DIM) ? wr[kk0 + 1] : 0.f;
    }
    __syncthreads();
#pragma unroll
    for (int kk = 0; kk < 8; kk++) {
      float a8[8], b4[4];
#pragma unroll
      for (int i = 0; i < 8; i++) a8[i] = As[kk][ty * 8 + i];
#pragma unroll
      for (int j = 0; j < 4; j++) b4[j] = Bs[kk][tx * 4 + j];
#pragma unroll
      for (int i = 0; i < 8; i++)
#pragma unroll
        for (int j = 0; j < 4; j++) acc[i][j] += a8[i] * b4[j];
    }
    __syncthreads();
  }
#pragma unroll
  for (int i = 0; i < 8; i++) {
    int hw = hw0 + ty * 8 + i;
#pragma unroll
    for (int j = 0; j < 4; j++) {
      int a = a0 + tx * 4 + j;
      ws[CT_OFF + hw * A_DIM + a] = acc[i][j] + bproj[a];
    }
  }
}

__global__ void k_gi(const float* __restrict__ emb_table, const float* __restrict__ Wih_in,
                     const float* __restrict__ bih_in, float* ws) {
  __shared__ float e_s[256];
  int v = blockIdx.x, tid = threadIdx.x;
  e_s[tid] = emb_table[v * 256 + tid];
  __syncthreads();
#pragma unroll
  for (int r = 0; r < 3; r++) {
    int m = r * 256 + tid;
    const float* wr = Wih_in + m * 256;
    float s = bih_in[m];
    for (int k = 0; k < 256; k++) s += e_s[k] * wr[k];
    ws[GI_OFF + v * 768 + m] = s;
  }
}

__global__ void k_se(const float* __restrict__ emb_table, const float* __restrict__ We,
                     const float* __restrict__ be, float* ws) {
  __shared__ float e_s[256];
  int v = blockIdx.x, tid = threadIdx.x;  // 128 threads
  e_s[tid] = emb_table[v * 256 + tid];
  e_s[tid + 128] = emb_table[v * 256 + tid + 128];
  __syncthreads();
  const float* wr = We + tid * 256;
  float s = be[tid];
  for (int k = 0; k < 256; k++) s += e_s[k] * wr[k];
  ws[SE_OFF + v * 128 + tid] = s;
}

__global__ void k_tr(const float* __restrict__ in, float* __restrict__ out, int M, int Kd) {
  int total = M * Kd;
  for (int i = blockIdx.x * blockDim.x + threadIdx.x; i < total; i += gridDim.x * blockDim.x) {
    int m = i / Kd, k = i - m * Kd;
    out[k * M + m] = in[i];
  }
}

__global__ void k_ghin0(float* ws) {
  __shared__ float hk[16];
  int b = blockIdx.x, tid = threadIdx.x;
  if (tid < 16) hk[tid] = ws[HBUF0_OFF + b * 16 + tid];
  __syncthreads();
  const float* wt = ws + WHHTIN_OFF;
#pragma unroll
  for (int r = 0; r < 3; r++) {
    int m = r * 256 + tid;
    float s = 0.f;
#pragma unroll
    for (int kk = 0; kk < 16; kk++) s += hk[kk] * wt[(b * 16 + kk) * 768 + m];
    ws[PGHIN0_OFF + b * 768 + m] = s;
  }
}

// ---------------- persistent all-steps kernel ----------------

__global__ __launch_bounds__(512) void k_steps(
    const float* __restrict__ cnn,
    const float* __restrict__ bq, const float* __restrict__ wa, const float* __restrict__ ba,
    const float* __restrict__ bih_out, const float* __restrict__ bhh_out,
    const float* __restrict__ bhh_in,
    const float* __restrict__ bs_, const float* __restrict__ bc_, const float* __restrict__ bv_,
    float* ws, float* __restrict__ out) {
  __shared__ float sm_gio[768], sm_gho[768];
  __shared__ float sm_h1[256], sm_h[256], sm_state[128];
  __shared__ float sm_patch[11][32];
  __shared__ float sm_red[8][16];
  __shared__ float sm_ctx[4];
  __shared__ float sm_val[512];
  __shared__ int sm_idx[512];

  const int bid = blockIdx.x, tid = threadIdx.x;
  int* cnt = (int*)ws + BAR_OFF;
  int* gen = (int*)ws + BAR_OFF + 1;
  const int lane = tid & 63, wv = tid >> 6;

#pragma unroll 1
  for (int t = 0; t < T_STEPS; t++) {
    // ---- S1: h1 + q/gho partials (blocks 0..15) ----
    if (bid < NSEG) {
      int word = ((const int*)ws)[WORDS_OFF + (t & 1)];
      if (tid < 256) sm_h1[tid] = compute_h1_row(ws, tid, word, t, bhh_in);
      __syncthreads();
      int k0 = bid * 16;
      float hk[16];
#pragma unroll
      for (int kk = 0; kk < 16; kk++) hk[kk] = sm_h1[k0 + kk];
      {
        float s = 0.f;
#pragma unroll
        for (int kk = 0; kk < 16; kk++) s += hk[kk] * ws[WQT_OFF + (k0 + kk) * 512 + tid];
        ws[PQ_OFF + bid * 512 + tid] = s;
      }
      for (int m = tid; m < 768; m += 512) {
        float s = 0.f;
#pragma unroll
        for (int kk = 0; kk < 16; kk++) s += hk[kk] * ws[WHHTOUT_OFF + (k0 + kk) * 768 + m];
        ws[PGHO_OFF + bid * 768 + m] = s;
      }
    }
    gbar(cnt, gen);

    // ---- S2: energy + exp (all 256 blocks, 16 hw each) ----
    {
      int h = bid >> 3, w0 = (bid & 7) * 16;
      int a = tid;
      float qa = bq[a];
#pragma unroll
      for (int s = 0; s < NSEG; s++) qa += ws[PQ_OFF + s * 512 + a];
      for (int i = tid; i < 11 * 26; i += 512) {
        int r = i / 26, c = i - r * 26;
        sm_patch[r][c] = ws[APAD_OFF + (h + r) * PADC + w0 + c];
      }
      __syncthreads();
      float acc[16];
#pragma unroll
      for (int i = 0; i < 16; i++) acc[i] = 0.f;
      const float* km = ws + KM_OFF;
      for (int dy = 0; dy < 11; dy++) {
        float row[26];
#pragma unroll
        for (int i = 0; i < 26; i++) row[i] = sm_patch[dy][i];
        float kv[11];
#pragma unroll
        for (int dx = 0; dx < 11; dx++) kv[dx] = km[(dy * 11 + dx) * A_DIM + a];
#pragma unroll
        for (int dx = 0; dx < 11; dx++)
#pragma unroll
          for (int wi = 0; wi < 16; wi++) acc[wi] += kv[dx] * row[wi + dx];
      }
      float waa = wa[a];
      int hw0 = h * WF + w0;
#pragma unroll
      for (int wi = 0; wi < 16; wi++) {
        float x = acc[wi] + qa + ws[CT_OFF + (hw0 + wi) * A_DIM + a];
        float p = ftanh(x) * waa;
#pragma unroll
        for (int off = 32; off; off >>= 1) p += __shfl_xor(p, off, 64);
        if (lane == 0) sm_red[wv][wi] = p;
      }
      __syncthreads();
      if (tid < 16) {
        float e = ba[0];
#pragma unroll
        for (int w2 = 0; w2 < 8; w2++) e += sm_red[w2][tid];
        int hw = hw0 + tid;
        float ev = (ws[MASK_OFF + hw] > 0.f) ? __expf(e) : 0.f;
        ws[EXP_OFF + hw] = ev;
        sm_val[tid] = ev;
      }
      __syncthreads();
      if (tid == 0) {
        float s = 0.f;
#pragma unroll
        for (int i = 0; i < 16; i++) s += sm_val[i];
        ws[PSUM_OFF + bid] = s;
      }
    }
    gbar(cnt, gen);

    // ---- S3: ctx + gio/psc partials (blocks 0..170); apad update (171..178) ----
    if (bid < NCTX + 8) {
      float S = 0.f;
      for (int i = 0; i < NBLK; i++) S += ws[PSUM_OFF + i];
      float inv = 1.f / S;
      if (bid < NCTX) {
        float al[8];
#pragma unroll
        for (int j = 0; j < 8; j++) al[j] = ws[EXP_OFF + j * 512 + tid] * inv;
        int c0 = bid * 4;
#pragma unroll
        for (int cc = 0; cc < 4; cc++) {
          const float* row = cnn + (c0 + cc) * HW;
          float p = 0.f;
#pragma unroll
          for (int j = 0; j < 8; j++) p += al[j] * row[j * 512 + tid];
#pragma unroll
          for (int off = 32; off; off >>= 1) p += __shfl_xor(p, off, 64);
          if (lane == 0) sm_red[wv][cc] = p;
        }
        __syncthreads();
        if (tid < 4) {
          float cv = 0.f;
#pragma unroll
          for (int w2 = 0; w2 < 8; w2++) cv += sm_red[w2][tid];
          sm_ctx[tid] = cv;
        }
        __syncthreads();
        for (int m = tid; m < 768; m += 512) {
          float s = 0.f;
#pragma unroll
          for (int cc = 0; cc < 4; cc++) s += sm_ctx[cc] * ws[WIHTOUT_OFF + (c0 + cc) * 768 + m];
          ws[PGIO2_OFF + bid * 768 + m] = s;
        }
        if (tid < 128) {
          float s = 0.f;
#pragma unroll
          for (int cc = 0; cc < 4; cc++) s += sm_ctx[cc] * ws[WCT_OFF + (c0 + cc) * 128 + tid];
          ws[PSC2_OFF + bid * 128 + tid] = s;
        }
      } else {
        int idx = (bid - NCTX) * 512 + tid;
        int hh = idx >> 7, ww = idx & 127;
        ws[APAD_OFF + (hh + 5) * PADC + ww + 5] += ws[EXP_OFF + idx] * inv;
      }
    }
    gbar(cnt, gen);

    // ---- S4: reduce -> h; block16: state/prob/argmax; blocks 0..15: ghin ----
    if (bid <= NSEG) {
      int word = ((const int*)ws)[WORDS_OFF + (t & 1)];
      for (int m = tid; m < 768; m += 512) {
        float g1 = bih_out[m];
        for (int s = 0; s < NCTX; s++) g1 += ws[PGIO2_OFF + s * 768 + m];
        float g2 = bhh_out[m];
#pragma unroll
        for (int s = 0; s < NSEG; s++) g2 += ws[PGHO_OFF + s * 768 + m];
        sm_gio[m] = g1;
        sm_gho[m] = g2;
      }
      if (tid < 256) sm_h1[tid] = compute_h1_row(ws, tid, word, t, bhh_in);
      __syncthreads();
      if (tid < 256) {
        float r = sigmoidf_(sm_gio[tid] + sm_gho[tid]);
        float z = sigmoidf_(sm_gio[256 + tid] + sm_gho[256 + tid]);
        float n = tanhf(sm_gio[512 + tid] + r * sm_gho[512 + tid]);
        float hv = (1.f - z) * n + z * sm_h1[tid];
        sm_h[tid] = hv;
        if (bid == NSEG) ws[(((t + 1) & 1) ? HBUF1_OFF : HBUF0_OFF) + tid] = hv;
      }
      __syncthreads();
      if (bid < NSEG) {
        float hk[16];
#pragma unroll
        for (int kk = 0; kk < 16; kk++) hk[kk] = sm_h[bid * 16 + kk];
        float* dst = ws + (((t + 1) & 1) ? PGHIN1_OFF : PGHIN0_OFF);
        for (int m = tid; m < 768; m += 512) {
          float s = 0.f;
#pragma unroll
          for (int kk = 0; kk < 16; kk++) s += hk[kk] * ws[WHHTIN_OFF + (bid * 16 + kk) * 768 + m];
          dst[bid * 768 + m] = s;
        }
      } else {
        // bid == 16: state, prob, argmax
        if (tid < 128) {
          float s = bs_[tid] + bc_[tid] + ws[SE_OFF + word * 128 + tid];
          for (int sg = 0; sg < NCTX; sg++) s += ws[PSC2_OFF + sg * 128 + tid];
          for (int k = 0; k < 256; k++) s += sm_h[k] * ws[WST_OFF + k * 128 + tid];
          sm_state[tid] = s;
        }
        __syncthreads();
        float best = -3.4e38f;
        int bi2 = 0;
        if (tid < V_DIM) {
          float p = bv_[tid];
          for (int k = 0; k < 128; k++) p += sm_state[k] * ws[WVT_OFF + k * V_DIM + tid];
          out[t * V_DIM + tid] = p;
          best = p;
          bi2 = tid;
        }
        sm_val[tid] = best;
        sm_idx[tid] = bi2;
        __syncthreads();
        for (int mstep = 256; mstep >= 1; mstep >>= 1) {
          if (tid < mstep) {
            float ov = sm_val[tid + mstep];
            int oi = sm_idx[tid + mstep];
            if (ov > sm_val[tid] || (ov == sm_val[tid] && oi < sm_idx[tid])) {
              sm_val[tid] = ov;
              sm_idx[tid] = oi;
            }
          }
          __syncthreads();
        }
        if (tid == 0) ((int*)ws)[WORDS_OFF + ((t + 1) & 1)] = sm_idx[0];
      }
    }
    gbar(cnt, gen);
  }
}

// ---------------- host ----------------

extern "C" void kernel_launch(void* const* d_in, const int* in_sizes, int n_in,
                              void* d_out, int out_size, void* d_ws, size_t ws_size,
                              hipStream_t stream) {
  (void)in_sizes; (void)n_in; (void)out_size; (void)ws_size;
  const float* cnn      = (const float*)d_in[0];
  const float* imask    = (const float*)d_in[1];
  const float* emb_tab  = (const float*)d_in[2];
  const float* W_init   = (const float*)d_in[3];
  const float* b_init   = (const float*)d_in[4];
  const float* Wih_in   = (const float*)d_in[5];
  const float* Whh_in   = (const float*)d_in[6];
  const float* bih_in   = (const float*)d_in[7];
  const float* bhh_in   = (const float*)d_in[8];
  const float* Wih_out  = (const float*)d_in[9];
  const float* Whh_out  = (const float*)d_in[10];
  const float* bih_out  = (const float*)d_in[11];
  const float* bhh_out  = (const float*)d_in[12];
  const float* Wq       = (const float*)d_in[13];
  const float* bq       = (const float*)d_in[14];
  const float* Wproj    = (const float*)d_in[15];
  const float* bproj    = (const float*)d_in[16];
  const float* convk    = (const float*)d_in[17];
  const float* Wcov     = (const float*)d_in[18];
  const float* wa       = (const float*)d_in[19];
  const float* ba       = (const float*)d_in[20];
  const float* Ws_      = (const float*)d_in[21];
  const float* bs_      = (const float*)d_in[22];
  const float* We_      = (const float*)d_in[23];
  const float* be_      = (const float*)d_in[24];
  const float* Wc_      = (const float*)d_in[25];
  const float* bc_      = (const float*)d_in[26];
  const float* Wv_      = (const float*)d_in[27];
  const float* bv_      = (const float*)d_in[28];
  float* ws  = (float*)d_ws;
  float* out = (float*)d_out;

  // one-time precompute
  k_init<<<1, 256, 0, stream>>>(imask, ws);
  k_avg<<<C_DIM, 256, 0, stream>>>(cnn, ws);
  k_h0<<<1, 256, 0, stream>>>(W_init, b_init, ws);
  k_km<<<121, 512, 0, stream>>>(convk, Wcov, ws);
  k_ct<<<dim3(HW / 128, A_DIM / 64), 256, 0, stream>>>(cnn, Wproj, bproj, ws);
  k_gi<<<V_DIM, 256, 0, stream>>>(emb_tab, Wih_in, bih_in, ws);
  k_se<<<V_DIM, 128, 0, stream>>>(emb_tab, We_, be_, ws);
  k_tr<<<512, 256, 0, stream>>>(Wq, ws + WQT_OFF, 512, 256);
  k_tr<<<512, 256, 0, stream>>>(Whh_in, ws + WHHTIN_OFF, 768, 256);
  k_tr<<<512, 256, 0, stream>>>(Whh_out, ws + WHHTOUT_OFF, 768, 256);
  k_tr<<<512, 256, 0, stream>>>(Wih_out, ws + WIHTOUT_OFF, 768, 684);
  k_tr<<<512, 256, 0, stream>>>(Wc_, ws + WCT_OFF, 128, 684);
  k_tr<<<512, 256, 0, stream>>>(Ws_, ws + WST_OFF, 128, 256);
  k_tr<<<512, 256, 0, stream>>>(Wv_, ws + WVT_OFF, 415, 128);
  k_ghin0<<<16, 256, 0, stream>>>(ws);

  // all 64 steps in one persistent kernel
  k_steps<<<NBLK, 512, 0, stream>>>(cnn, bq, wa, ba, bih_out, bhh_out, bhh_in,
                                    bs_, bc_, bv_, ws, out);
}